// Round 5
// baseline (171.212 us; speedup 1.0000x reference)
//
#include <hip/hip_runtime.h>
#include <math.h>

#define B 4
#define C 384
#define HIN 224
#define WIN 224
#define KS 14
#define HB 16
#define WBL 16
#define P 196            // KS*KS
#define ROWDW 101        // dwords per channel row in LDS (98 data + 3 pad; gcd(101,32)=1)

// round-to-nearest-even f32 -> bf16 bits
__device__ __forceinline__ unsigned int f2bf(float f) {
    union { float f; unsigned int u; } c; c.f = f;
    return (c.u + 0x7fffu + ((c.u >> 16) & 1u)) >> 16;
}
__device__ __forceinline__ float bf2f(unsigned int bits16) {
    union { unsigned int u; float f; } c; c.u = bits16 << 16;
    return c.f;
}

// ---------------------------------------------------------------------------
// Single-pass fused kernel. One block per (b, hb, wb) patch-block.
// The 196x384 patch is read from HBM ONCE, held in LDS as bf16, and used
// for both the logit computation and the softmax-weighted reduction.
// ---------------------------------------------------------------------------
__global__ __launch_bounds__(512, 2) void k_fused(const float* __restrict__ hr,
                                                  const float* __restrict__ attn_w,
                                                  const float* __restrict__ attn_b,
                                                  const float* __restrict__ w_kk,
                                                  const float* __restrict__ b_kk,
                                                  const int* __restrict__ mask,
                                                  float* __restrict__ out) {
    __shared__ unsigned int x4[C * ROWDW];        // 384 rows * 404 B = 155,136 B
    __shared__ __align__(8) float e_lds[200];     // exp weights (f32, padded)
    __shared__ float wlds[C];
    __shared__ float plds[392];                   // logit partials (2 c-halves)
    __shared__ float smax[8], ssum[8];
    const int tid = threadIdx.x;
    const int blk = blockIdx.x;
    const int wb = blk & 15, hb = (blk >> 4) & 15, b = blk >> 8;

    if (tid < C) wlds[tid] = attn_w[tid];

    // ---- phase 1: global -> bf16 LDS (thread = channel) ----
    if (tid < C) {
        const float* src = hr + ((size_t)(b * C + tid) * HIN + hb * KS) * WIN + wb * KS;
        unsigned int* xrow = x4 + tid * ROWDW;
        #pragma unroll
        for (int ki = 0; ki < KS; ++ki) {
            const float2* r = reinterpret_cast<const float2*>(src + (size_t)ki * WIN);
            #pragma unroll
            for (int j = 0; j < 7; ++j) {
                const float2 v = r[j];
                xrow[ki * 7 + j] = f2bf(v.x) | (f2bf(v.y) << 16);
            }
        }
    }
    __syncthreads();

    // ---- phase 2: logits. thread = (p, c-half); reduce 192 channels each ----
    if (tid < 392) {
        const int p = tid % P, cs = tid / P;
        const int dj = p >> 1, sh = (p & 1) << 4;
        const int c0 = cs * 192;
        float part = 0.f;
        #pragma unroll 8
        for (int c = c0; c < c0 + 192; ++c) {
            const unsigned int u = x4[c * ROWDW + dj];
            part += bf2f((u >> sh) & 0xffffu) * wlds[c];
        }
        plds[tid] = part;
    }
    __syncthreads();

    float l = -INFINITY;
    if (tid < P) {
        const float rv = plds[tid] + plds[P + tid];
        const float m = mask[(b * HB + hb) * WBL + wb] ? 1.f : 0.f;
        l = (rv + attn_b[0]) * m * w_kk[tid] + b_kk[tid];
    }

    // ---- phase 3: block softmax over 196 logits (8 waves) ----
    float v = l;
    #pragma unroll
    for (int off = 32; off; off >>= 1) v = fmaxf(v, __shfl_xor(v, off));
    if ((tid & 63) == 0) smax[tid >> 6] = v;
    __syncthreads();
    float bm = smax[0];
    #pragma unroll
    for (int k = 1; k < 8; ++k) bm = fmaxf(bm, smax[k]);

    const float e = (tid < P) ? __expf(l - bm) : 0.f;
    float s = e;
    #pragma unroll
    for (int off = 32; off; off >>= 1) s += __shfl_xor(s, off);
    if ((tid & 63) == 0) ssum[tid >> 6] = s;
    if (tid < P) e_lds[tid] = e;
    __syncthreads();
    const float S = ((ssum[0] + ssum[1]) + (ssum[2] + ssum[3]))
                  + ((ssum[4] + ssum[5]) + (ssum[6] + ssum[7]));

    // ---- phase 4: weighted reduction (thread = channel, reads own LDS row) ----
    if (tid < C) {
        const unsigned int* xrow = x4 + tid * ROWDW;
        const float2* e2 = reinterpret_cast<const float2*>(e_lds);
        float acc = 0.f;
        #pragma unroll 14
        for (int d = 0; d < 98; ++d) {
            const unsigned int u = xrow[d];
            const float2 ee = e2[d];
            acc += ee.x * bf2f(u & 0xffffu) + ee.y * bf2f(u >> 16);
        }
        out[((size_t)(b * C + tid) * HB + hb) * WBL + wb] = acc / S;
    }
}

extern "C" void kernel_launch(void* const* d_in, const int* in_sizes, int n_in,
                              void* d_out, int out_size, void* d_ws, size_t ws_size,
                              hipStream_t stream) {
    const float* hr      = (const float*)d_in[0];  // (4,384,224,224)
    // d_in[1] = guidance (unused)
    const float* attn_w  = (const float*)d_in[2];  // (1,384)
    const float* attn_b  = (const float*)d_in[3];  // (1,)
    const float* w_kk    = (const float*)d_in[4];  // (14,14)
    const float* b_kk    = (const float*)d_in[5];  // (14,14)
    const int*   mask    = (const int*)d_in[6];    // (4,16,16,1) bool->int
    float* out = (float*)d_out;                    // (4,384,16,16)

    k_fused<<<B * HB * WBL, 512, 0, stream>>>(hr, attn_w, attn_b, w_kk, b_kk, mask, out);
}

// Round 6
// 124.629 us; speedup vs baseline: 1.3738x; 1.3738x over previous
//
#include <hip/hip_runtime.h>
#include <math.h>

#define B 4
#define C 384
#define HIN 224
#define WIN 224
#define KS 14
#define HB 16
#define WBL 16
#define P 196
#define NR 2                  // patch rows per chunk
#define NP (NR * KS)          // 28 p-values per chunk
#define NCHK (KS / NR)        // 7 chunks
#define XST 30                // x_lds channel stride in floats (even for float2; 2-way bank alias = free)

// ---------------------------------------------------------------------------
// Single-pass online-softmax fused kernel. One block per (b,hb,wb) patch.
// Streams the 14 patch rows in 7 chunks of 2; each chunk lives briefly in a
// 45KB fp32 LDS buffer (3 blocks/CU co-resident -> loads of one block overlap
// compute of others). Running (m,l,o[c]) flash-style state; hr read ONCE.
// XCD-chunked swizzle co-locates each strip's 16 wb-blocks on one XCD so
// their overlapping cache lines hit L2 instead of refetching HBM.
// ---------------------------------------------------------------------------
__global__ __launch_bounds__(512, 6) void k_online(const float* __restrict__ hr,
                                                   const float* __restrict__ attn_w,
                                                   const float* __restrict__ attn_b,
                                                   const float* __restrict__ w_kk,
                                                   const float* __restrict__ b_kk,
                                                   const int* __restrict__ mask,
                                                   float* __restrict__ out) {
    __shared__ float x_lds[C * XST];        // 46,080 B
    __shared__ float wlds[C];
    __shared__ float wkk[P], bkk[P];
    __shared__ float plds[16 * NP];         // logit partials [cg][pp]
    __shared__ float e_l[NP];
    __shared__ float st_f, st_l;

    const int tid = threadIdx.x;
    const int bid = blockIdx.x;
    const int swz = (bid & 7) * 128 + (bid >> 3);   // bijective XCD-chunked swizzle
    const int wb = swz & 15, hb = (swz >> 4) & 15, b = swz >> 8;

    if (tid < C) wlds[tid] = attn_w[tid];
    if (tid < P) { wkk[tid] = w_kk[tid]; bkk[tid] = b_kk[tid]; }

    const float mval = mask[(b * HB + hb) * WBL + wb] ? 1.f : 0.f;
    const float ab = attn_b[0];
    const float* hr_base = hr + ((size_t)(b * C) * HIN + hb * KS) * WIN + wb * KS;

    float m_run = -INFINITY, l_run = 0.f;   // uniform across wave 0
    float o = 0.f;                          // thread = channel accumulator
    __syncthreads();                        // wlds/wkk ready

    for (int ch = 0; ch < NCHK; ++ch) {
        // ---- phase 1: load chunk rows (2ch, 2ch+1) -> LDS fp32 ----
        for (int i = tid; i < C * NR * 7; i += 512) {
            const int c = i / (NR * 7);
            const int rr = i % (NR * 7);
            const int r = rr / 7, j = rr % 7;
            const float2 v = *reinterpret_cast<const float2*>(
                hr_base + ((size_t)c * HIN + ch * NR + r) * WIN + j * 2);
            *reinterpret_cast<float2*>(&x_lds[c * XST + r * KS + j * 2]) = v;
        }
        __syncthreads();

        // ---- phase 2: logit partials. thread=(cg,pp): 24 channels each ----
        if (tid < 16 * NP) {
            const int cg = tid / NP, pp = tid % NP;
            const int c0 = cg * 24;
            float s = 0.f;
            #pragma unroll 8
            for (int i = 0; i < 24; ++i)
                s += x_lds[(c0 + i) * XST + pp] * wlds[c0 + i];
            plds[cg * NP + pp] = s;
        }
        __syncthreads();

        // ---- phase 3: finish logits + online softmax update (wave 0) ----
        if (tid < 64) {
            float lg = -INFINITY;
            if (tid < NP) {
                float s = 0.f;
                #pragma unroll
                for (int g = 0; g < 16; ++g) s += plds[g * NP + tid];
                const int pg = ch * NP + tid;
                lg = (s + ab) * mval * wkk[pg] + bkk[pg];
            }
            float cm = lg;
            #pragma unroll
            for (int off = 32; off; off >>= 1) cm = fmaxf(cm, __shfl_xor(cm, off));
            const float m_new = fmaxf(m_run, cm);
            const float f = __expf(m_run - m_new);
            const float e = (tid < NP) ? __expf(lg - m_new) : 0.f;
            float se = e;
            #pragma unroll
            for (int off = 32; off; off >>= 1) se += __shfl_xor(se, off);
            l_run = l_run * f + se;
            m_run = m_new;
            if (tid < NP) e_l[tid] = e;
            if (tid == 0) st_f = f;
        }
        __syncthreads();

        // ---- phase 4: rescale + accumulate (thread = channel) ----
        const float f = st_f;
        if (tid < C) {
            float acc = 0.f;
            #pragma unroll
            for (int p = 0; p < NP; ++p)
                acc += e_l[p] * x_lds[tid * XST + p];
            o = o * f + acc;
        }
        __syncthreads();   // x_lds free for next chunk
    }

    if (tid == 0) st_l = l_run;
    __syncthreads();
    if (tid < C)
        out[((size_t)(b * C + tid) * HB + hb) * WBL + wb] = o / st_l;
}

extern "C" void kernel_launch(void* const* d_in, const int* in_sizes, int n_in,
                              void* d_out, int out_size, void* d_ws, size_t ws_size,
                              hipStream_t stream) {
    const float* hr      = (const float*)d_in[0];  // (4,384,224,224)
    // d_in[1] = guidance (unused)
    const float* attn_w  = (const float*)d_in[2];  // (1,384)
    const float* attn_b  = (const float*)d_in[3];  // (1,)
    const float* w_kk    = (const float*)d_in[4];  // (14,14)
    const float* b_kk    = (const float*)d_in[5];  // (14,14)
    const int*   mask    = (const int*)d_in[6];    // (4,16,16,1) bool->int
    float* out = (float*)d_out;                    // (4,384,16,16)

    k_online<<<B * HB * WBL, 512, 0, stream>>>(hr, attn_w, attn_b, w_kk, b_kk, mask, out);
}